// Round 4
// baseline (760.875 us; speedup 1.0000x reference)
//
#include <hip/hip_runtime.h>
#include <stdint.h>

#define BDIM   1024
#define NROWS  32
#define CDIM   1024
#define NSTEPS (NROWS - 1)
#define BATCH  512
#define ROWS_LDS_BYTES (NROWS * CDIM * sizeof(float))  // 128 KB

// One 1024-thread workgroup per batch; whole 31-step merge chain in-block.
// ALL row data LDS-resident (32 slots x 4KB fp32, dynamic LDS). Merged row
// always overwrites slot(bb) (provably dead after every merge, incl. the
// a==1 reference quirk where old row 0 is dropped). Distance matrix D is
// SLOT-indexed fp64 (no remap, no ping-pong): only row/col of the merged
// slot changes per step. Logical order kept as idx[] (logical pos -> slot),
// ping-ponged; argmin iterates logical pairs for reference-exact flat-index
// tie-breaking ((float)sqrt(fp64 d2) key).
__global__ __launch_bounds__(BDIM)
void merge_tree_kernel(const float* __restrict__ xin,  // B*32*1024 fp32
                       const float* __restrict__ wz,   // 6 fp32 (1,2,3)
                       const float* __restrict__ bz,   // 1 fp32
                       float* __restrict__ out)        // B*1024 fp32
{
    extern __shared__ float rows[];                    // [NROWS][CDIM]

    const int b    = blockIdx.x;
    const int tid  = threadIdx.x;
    const int lane = tid & 63;
    const int wid  = tid >> 6;   // 0..15
    const int g32  = tid >> 5;   // 0..31
    const int j32  = tid & 31;

    const float* xb = xin + (size_t)b * NROWS * CDIM;

    __shared__ double D[NROWS][NROWS + 1];   // slot-indexed d2
    __shared__ double sq[NROWS];             // slot-indexed squared norms
    __shared__ int    idxbuf[2][NROWS];      // logical pos -> slot
    __shared__ double wredv[16];
    __shared__ int    wredp[16];
    __shared__ double wsum[16];
    __shared__ int    sAB[2];

    float W0[3], W1[3];
    #pragma unroll
    for (int k = 0; k < 3; k++) { W0[k] = wz[k]; W1[k] = wz[3 + k]; }
    const float CB = bz[0];

    // dot of two LDS rows by one 32-lane group (float4 -> fp64 acc);
    // result valid at group lane 0 (and via shuffle pattern at j32==0)
    auto grpDot = [&](const float* ra, const float* rb) -> double {
        const float4* A = (const float4*)ra;
        const float4* B = (const float4*)rb;
        double acc = 0.0;
        #pragma unroll
        for (int t = 0; t < 8; t++) {
            float4 a = A[j32 + 32 * t];
            float4 v = B[j32 + 32 * t];
            acc += (double)a.x * (double)v.x + (double)a.y * (double)v.y
                 + (double)a.z * (double)v.z + (double)a.w * (double)v.w;
        }
        #pragma unroll
        for (int off = 16; off > 0; off >>= 1) acc += __shfl_down(acc, off, 64);
        return acc;
    };

    // ---------- stage all rows global -> LDS (coalesced float4) ----------
    {
        float4* rv = (float4*)rows;
        const float4* xv = (const float4*)xb;
        #pragma unroll
        for (int t = tid; t < NROWS * CDIM / 4; t += BDIM) rv[t] = xv[t];
        if (tid < NROWS) idxbuf[0][tid] = tid;
    }
    __syncthreads();

    // ---------- squared norms: group g -> slot g ----------
    {
        const float4* P = (const float4*)(rows + g32 * CDIM);
        double acc = 0.0;
        #pragma unroll
        for (int t = 0; t < 8; t++) {
            float4 a = P[j32 + 32 * t];
            acc += (double)a.x * (double)a.x + (double)a.y * (double)a.y
                 + (double)a.z * (double)a.z + (double)a.w * (double)a.w;
        }
        #pragma unroll
        for (int off = 16; off > 0; off >>= 1) acc += __shfl_down(acc, off, 64);
        if (j32 == 0) sq[g32] = acc;
    }
    __syncthreads();

    // ---------- init pairwise D (496 pairs over 32 groups) ----------
    for (int v = g32; v < (NROWS * (NROWS - 1)) / 2; v += 32) {
        int r = v, d = 1;
        while (r >= NROWS - d) { r -= NROWS - d; d++; }
        int i = r, j = i + d;
        double dot = grpDot(rows + i * CDIM, rows + j * CDIM);
        if (j32 == 0) {
            double dv = sq[i] + sq[j] - 2.0 * dot;
            D[i][j] = dv;
            D[j][i] = dv;
        }
    }
    __syncthreads();

    // ---------- main merge loop ----------
    int p = 0;
    float lastm = 0.0f;
    for (int step = 0; step < NSTEPS; step++) {
        const int n  = NROWS - step;
        const int m1 = n - 1;
        int* idx  = idxbuf[p];
        int* nidx = idxbuf[p ^ 1];

        // --- argmin over logical pairs (i<j): key=(fp32 dist, flat) ---
        double bv = 1e300;
        int    bp = 0x7fffffff;
        if (tid < n * n) {
            int i = tid / n, j = tid - i * n;
            if (j > i) {
                double d2 = D[idx[i]][idx[j]];
                float  df = (float)((d2 > 0.0) ? sqrt(d2) : 0.0);
                bv = (double)df; bp = tid;
            }
        }
        #pragma unroll
        for (int off = 32; off > 0; off >>= 1) {
            double ov = __shfl_down(bv, off); int op = __shfl_down(bp, off);
            if (ov < bv || (ov == bv && op < bp)) { bv = ov; bp = op; }
        }
        if (lane == 0) { wredv[wid] = bv; wredp[wid] = bp; }
        __syncthreads();                                   // B1
        if (wid == 0) {
            double v = (lane < 16) ? wredv[lane] : 1e300;
            int    q = (lane < 16) ? wredp[lane] : 0x7fffffff;
            #pragma unroll
            for (int off = 8; off > 0; off >>= 1) {
                double ov = __shfl_down(v, off); int oq = __shfl_down(q, off);
                if (ov < v || (ov == v && oq < q)) { v = ov; q = oq; }
            }
            if (lane == 0) { sAB[0] = q / n; sAB[1] = q % n; }
        }
        __syncthreads();                                   // B2

        const int a  = sAB[0];
        const int bb = sAB[1];
        const int sa = idx[a], sb = idx[bb];
        const float* pa = rows + sa * CDIM;
        const float* pb = rows + sb * CDIM;

        // --- conv merge: read 6 neighbors into regs BEFORE overwrite ---
        const int h = tid;
        float am1 = (h > 0)        ? pa[h - 1] : 0.0f;
        float bm1 = (h > 0)        ? pb[h - 1] : 0.0f;
        float a0  = pa[h],          b0 = pb[h];
        float ap1 = (h < CDIM - 1) ? pa[h + 1] : 0.0f;
        float bp1 = (h < CDIM - 1) ? pb[h + 1] : 0.0f;
        double acc = (double)CB
                   + (double)W0[0] * (double)am1 + (double)W1[0] * (double)bm1
                   + (double)W0[1] * (double)a0  + (double)W1[1] * (double)b0
                   + (double)W0[2] * (double)ap1 + (double)W1[2] * (double)bp1;
        float m = (acc > 0.0) ? (float)acc : 0.0f;
        lastm = m;
        __syncthreads();                                   // B3 (reads done)

        rows[sb * CDIM + h] = m;                           // merged -> slot sb
        {
            double s = (double)m * (double)m;
            #pragma unroll
            for (int off = 32; off > 0; off >>= 1) s += __shfl_down(s, off);
            if (lane == 0) wsum[wid] = s;
        }
        // new logical order: new[0]=merged(sb); new[k-1]=old[k] with
        // overrides pos bb<-old1, pos a<-old0 (a==1 drops old0 — ref quirk)
        if (tid == 0) nidx[0] = sb;
        if (tid >= 1 && tid < m1) {
            int k = tid + 1;
            int src = (k == bb) ? 1 : ((k == a) ? 0 : k);
            nidx[tid] = idx[src];
        }
        __syncthreads();                                   // B4 (row+wsum+nidx ready)

        // per-wave total sq of merged row (no extra barrier)
        double sv = (lane < 16) ? wsum[lane] : 0.0;
        #pragma unroll
        for (int off = 8; off > 0; off >>= 1) sv += __shfl_down(sv, off);
        const double sqm = __shfl(sv, 0, 64);
        if (tid == 0) sq[sb] = sqm;

        // --- dots merged-vs-survivors: group g -> logical l=1+g ---
        {
            const int l = 1 + g32;
            if (l < m1) {
                const int sl = nidx[l];
                double dot = grpDot(rows + sb * CDIM, rows + sl * CDIM);
                if (j32 == 0) {
                    double v = sqm + sq[sl] - 2.0 * dot;
                    D[sb][sl] = v;
                    D[sl][sb] = v;
                }
            }
        }
        __syncthreads();                                   // B5
        p ^= 1;
    }

    out[(size_t)b * CDIM + tid] = lastm;
}

extern "C" void kernel_launch(void* const* d_in, const int* in_sizes, int n_in,
                              void* d_out, int out_size, void* d_ws, size_t ws_size,
                              hipStream_t stream) {
    const float* x  = (const float*)d_in[0]; // fp32 (512,32,1024)
    const float* w  = (const float*)d_in[1]; // fp32 (1,2,3)
    const float* cb = (const float*)d_in[2]; // fp32 (1,)
    float* out = (float*)d_out;              // fp32 (512,1024)
    (void)d_ws; (void)ws_size; (void)in_sizes; (void)n_in;

    // allow >64KB dynamic LDS (160 KB/CU on gfx950); ignore result if no-op
    (void)hipFuncSetAttribute((const void*)merge_tree_kernel,
                              hipFuncAttributeMaxDynamicSharedMemorySize,
                              (int)ROWS_LDS_BYTES);

    hipLaunchKernelGGL(merge_tree_kernel, dim3(BATCH), dim3(BDIM),
                       ROWS_LDS_BYTES, stream, x, w, cb, out);
}

// Round 5
// 684.378 us; speedup vs baseline: 1.1118x; 1.1118x over previous
//
#include <hip/hip_runtime.h>
#include <stdint.h>

#define BDIM    1024
#define NROWS   32
#define NSLOT   33                    // 32 alive + 1 rotating spare
#define CDIM    1024
#define RSTRIDE 1028                  // floats/row in LDS: 16B-aligned, +4 banks per row
#define NSTEPS  (NROWS - 1)
#define BATCH   512
#define LDS_DYN_BYTES (NSLOT * RSTRIDE * sizeof(float))   // 135,696 B

// One 1024-thread block per batch; whole 31-step merge chain in-block.
// All row data LDS-resident (33 slots). Merged row written to the rotating
// SPARE slot (never read this step -> no read/write barrier); spare_next =
// slot(bb), dead after every merge incl. the a==1 reference quirk.
// Distances: fp64 diff-form sum((xi-xj)^2), slot-indexed D (no remap,
// no sq-norm bookkeeping). Argmin: ONE wave, key = fp64 d2 (sqrt is
// monotone; reference flat-index tie-break preserved via (d2, flat)).
// 3 barriers/step.
__global__ __launch_bounds__(BDIM)
void merge_tree_kernel(const float* __restrict__ xin,  // B*32*1024 fp32
                       const float* __restrict__ wz,   // 6 fp32 (1,2,3)
                       const float* __restrict__ bz,   // 1 fp32
                       float* __restrict__ out)        // B*1024 fp32
{
    extern __shared__ float rows[];                    // [NSLOT][RSTRIDE]

    const int b    = blockIdx.x;
    const int tid  = threadIdx.x;
    const int lane = tid & 63;
    const int wid  = tid >> 6;   // 0..15
    const int g32  = tid >> 5;   // 0..31
    const int j32  = tid & 31;

    const float* xb = xin + (size_t)b * NROWS * CDIM;

    __shared__ double D[NSLOT][NSLOT + 1];   // slot-indexed d2 (8976 B)
    __shared__ int    idxbuf[2][NROWS];      // logical pos -> slot
    __shared__ int    sAB[2];                // argmin (a, bb)

    float W0[3], W1[3];
    #pragma unroll
    for (int k = 0; k < 3; k++) { W0[k] = wz[k]; W1[k] = wz[3 + k]; }
    const float CB = bz[0];

    // fp64 diff-form distance^2 of two LDS rows by one 32-lane group;
    // valid at group lane 0 (j32==0)
    auto grpDist2 = [&](const float* ra, const float* rb) -> double {
        const float4* A = (const float4*)ra;
        const float4* B = (const float4*)rb;
        double acc = 0.0;
        #pragma unroll
        for (int t = 0; t < 8; t++) {
            float4 a = A[j32 + 32 * t];
            float4 v = B[j32 + 32 * t];
            double d0 = (double)a.x - (double)v.x;
            double d1 = (double)a.y - (double)v.y;
            double d2 = (double)a.z - (double)v.z;
            double d3 = (double)a.w - (double)v.w;
            acc += d0 * d0 + d1 * d1 + d2 * d2 + d3 * d3;
        }
        #pragma unroll
        for (int off = 16; off > 0; off >>= 1) acc += __shfl_down(acc, off, 64);
        return acc;
    };

    // ---------- stage rows global(1024-stride) -> LDS(1028-stride) ----------
    {
        float4* rv = (float4*)rows;
        const float4* xv = (const float4*)xb;
        for (int t = tid; t < NROWS * (CDIM / 4); t += BDIM) {
            int r = t >> 8, c = t & 255;                 // 256 float4 per row
            rv[r * (RSTRIDE / 4) + c] = xv[t];
        }
        if (tid < NROWS) idxbuf[0][tid] = tid;
    }
    __syncthreads();

    // ---------- init pairwise D (496 pairs over 32 groups) ----------
    for (int v = g32; v < (NROWS * (NROWS - 1)) / 2; v += 32) {
        int r = v, d = 1;
        while (r >= NROWS - d) { r -= NROWS - d; d++; }
        int i = r, j = i + d;
        double dv = grpDist2(rows + i * RSTRIDE, rows + j * RSTRIDE);
        if (j32 == 0) { D[i][j] = dv; D[j][i] = dv; }
    }
    __syncthreads();

    // ---------- main merge loop: 3 barriers per step ----------
    int p = 0;
    int sp = NROWS;                  // spare slot (32)
    float lastm = 0.0f;
    for (int step = 0; step < NSTEPS; step++) {
        const int n = NROWS - step;
        int* idx  = idxbuf[p];
        int* nidx = idxbuf[p ^ 1];

        // --- argmin on wave 0 only: key = (fp64 d2, flat) ---
        if (wid == 0) {
            const uint32_t M = 0xFFFFFFFFu / (uint32_t)n + 1;  // magic div, exact for flat<2^27
            double bk = 1e300;
            int    bp = 0x7fffffff;
            for (int flat = lane; flat < n * n; flat += 64) {
                int i = (int)__umulhi((uint32_t)flat, M);
                int j = flat - i * n;
                if (j > i) {
                    double d2 = D[idx[i]][idx[j]];
                    if (d2 < bk || (d2 == bk && flat < bp)) { bk = d2; bp = flat; }
                }
            }
            #pragma unroll
            for (int off = 32; off > 0; off >>= 1) {
                double ov = __shfl_down(bk, off); int op = __shfl_down(bp, off);
                if (ov < bk || (ov == bk && op < bp)) { bk = ov; bp = op; }
            }
            if (lane == 0) {
                int i = (int)__umulhi((uint32_t)bp, M);
                sAB[0] = i; sAB[1] = bp - i * n;
            }
        }
        __syncthreads();                                   // B1

        const int a  = sAB[0];
        const int bb = sAB[1];
        const int sa = idx[a], sb = idx[bb];
        const float* pa = rows + sa * RSTRIDE;
        const float* pb = rows + sb * RSTRIDE;

        // --- conv merge -> spare slot (no read/write hazard) ---
        const int h = tid;
        float am1 = (h > 0)        ? pa[h - 1] : 0.0f;
        float bm1 = (h > 0)        ? pb[h - 1] : 0.0f;
        float a0  = pa[h],          b0 = pb[h];
        float ap1 = (h < CDIM - 1) ? pa[h + 1] : 0.0f;
        float bp1 = (h < CDIM - 1) ? pb[h + 1] : 0.0f;
        double acc = (double)CB
                   + (double)W0[0] * (double)am1 + (double)W1[0] * (double)bm1
                   + (double)W0[1] * (double)a0  + (double)W1[1] * (double)b0
                   + (double)W0[2] * (double)ap1 + (double)W1[2] * (double)bp1;
        float m = (acc > 0.0) ? (float)acc : 0.0f;
        lastm = m;
        rows[sp * RSTRIDE + h] = m;

        // new logical order: new[0]=merged(sp); new[t]=old[t+1] with
        // overrides pos bb-1<-old[1], pos a-1<-old[0] (a==1 drops old[0])
        if (tid == 0) nidx[0] = sp;
        if (tid >= 1 && tid < n - 1) {
            int k = tid + 1;
            int src = (k == bb) ? 1 : ((k == a) ? 0 : k);
            nidx[tid] = idx[src];
        }
        __syncthreads();                                   // B2

        // --- distances merged-vs-survivors: group g -> logical l=1+g ---
        {
            const int l = 1 + g32;
            if (l < n - 1) {
                const int sl = nidx[l];
                double dv = grpDist2(rows + sp * RSTRIDE, rows + sl * RSTRIDE);
                if (j32 == 0) { D[sp][sl] = dv; D[sl][sp] = dv; }
            }
        }
        __syncthreads();                                   // B3

        sp = sb;                                           // sb provably dead
        p ^= 1;
    }

    out[(size_t)b * CDIM + tid] = lastm;
}

extern "C" void kernel_launch(void* const* d_in, const int* in_sizes, int n_in,
                              void* d_out, int out_size, void* d_ws, size_t ws_size,
                              hipStream_t stream) {
    const float* x  = (const float*)d_in[0]; // fp32 (512,32,1024)
    const float* w  = (const float*)d_in[1]; // fp32 (1,2,3)
    const float* cb = (const float*)d_in[2]; // fp32 (1,)
    float* out = (float*)d_out;              // fp32 (512,1024)
    (void)d_ws; (void)ws_size; (void)in_sizes; (void)n_in;

    (void)hipFuncSetAttribute((const void*)merge_tree_kernel,
                              hipFuncAttributeMaxDynamicSharedMemorySize,
                              (int)LDS_DYN_BYTES);

    hipLaunchKernelGGL(merge_tree_kernel, dim3(BATCH), dim3(BDIM),
                       LDS_DYN_BYTES, stream, x, w, cb, out);
}

// Round 6
// 530.494 us; speedup vs baseline: 1.4343x; 1.2901x over previous
//
#include <hip/hip_runtime.h>
#include <stdint.h>

#define NROWS   32
#define CDIM    1024
#define NSTEPS  31
#define BATCH   512
#define DSTRIDE 34                                   // D row stride (doubles)
#define DBYTES_PER_BATCH 9216                        // 33*34*8=8976 -> pad 9216
#define DAREA_TOTAL ((size_t)BATCH * DBYTES_PER_BATCH)
#define RSTRIDE 1028                                 // K1 LDS row stride (floats)
#define K1_LDS  (NROWS * RSTRIDE * sizeof(float))    // 131584 B

// ---------------- K1: init pairwise D (fp64 diff-form) ----------------
// One 1024-thread block per batch; stage 32 rows in LDS, 32 groups of 32
// lanes compute the 496 pair distances, write slot-indexed D to workspace.
__global__ __launch_bounds__(1024)
void init_d2_kernel(const float* __restrict__ xin, char* __restrict__ ws)
{
    extern __shared__ float rows[];
    const int b = blockIdx.x, tid = threadIdx.x;
    const int g32 = tid >> 5, j32 = tid & 31;
    const float* xb = xin + (size_t)b * NROWS * CDIM;
    double* Dg = (double*)(ws + (size_t)b * DBYTES_PER_BATCH);

    {
        float4* rv = (float4*)rows;
        const float4* xv = (const float4*)xb;
        for (int t = tid; t < NROWS * (CDIM / 4); t += 1024) {
            int r = t >> 8, c = t & 255;
            rv[r * (RSTRIDE / 4) + c] = xv[t];
        }
    }
    __syncthreads();

    for (int v = g32; v < (NROWS * (NROWS - 1)) / 2; v += 32) {
        int r = v, d = 1;
        while (r >= NROWS - d) { r -= NROWS - d; d++; }
        int i = r, j = i + d;
        const float4* A = (const float4*)(rows + i * RSTRIDE);
        const float4* B = (const float4*)(rows + j * RSTRIDE);
        double acc = 0.0;
        #pragma unroll
        for (int t = 0; t < 8; t++) {
            float4 a = A[j32 + 32 * t], vv = B[j32 + 32 * t];
            float d0 = a.x - vv.x, d1 = a.y - vv.y;
            float d2 = a.z - vv.z, d3 = a.w - vv.w;
            acc += (double)d0 * d0 + (double)d1 * d1
                 + (double)d2 * d2 + (double)d3 * d3;
        }
        #pragma unroll
        for (int off = 16; off > 0; off >>= 1) acc += __shfl_down(acc, off, 64);
        if (j32 == 0) { Dg[i * DSTRIDE + j] = acc; Dg[j * DSTRIDE + i] = acc; }
    }
}

// ---------------- K2: merge chain, ONE WAVE per batch, zero barriers ----
// D (slot-indexed fp64, 33 slots w/ rotating spare) + idx/rowaddr in LDS;
// merged-row chunk (16 floats, contiguous per lane) in registers; original
// rows read from d_in, merged rows appended to workspace. Argmin key =
// fp64 d2 + flat-index tiebreak (reference order; proven r4/r5). Merged row
// always takes spare D-slot; next spare = slot(bb) (dead every step, incl.
// the a==1 reference quirk where old row 0 is dropped).
__global__ __launch_bounds__(64)
void merge_kernel(const float* __restrict__ xin, const float* __restrict__ wz,
                  const float* __restrict__ bz, float* __restrict__ out,
                  char* __restrict__ ws)
{
    const int b = blockIdx.x, lane = threadIdx.x;
    const float* xb = xin + (size_t)b * NROWS * CDIM;
    const double* Dg = (const double*)(ws + (size_t)b * DBYTES_PER_BATCH);
    float* rg = (float*)(ws + DAREA_TOTAL + (size_t)b * (NSTEPS * (size_t)CDIM * 4));

    __shared__ double D[33][DSTRIDE];
    __shared__ int    idxbuf[2][NROWS];
    __shared__ int    rowaddr[33];      // D-slot -> row location (<32: input, >=32: ws row-32)

    for (int t = lane; t < 33 * DSTRIDE; t += 64) ((double*)D)[t] = Dg[t];
    if (lane < NROWS) { idxbuf[0][lane] = lane; rowaddr[lane] = lane; }
    __syncthreads();

    const float w00 = wz[0], w01 = wz[1], w02 = wz[2];
    const float w10 = wz[3], w11 = wz[4], w12 = wz[5];
    const float cb  = bz[0];

    float m[16];
    int p = 0, sp = 32;

    for (int step = 0; step < NSTEPS; step++) {
        const int n = NROWS - step;
        int* idx  = idxbuf[p];
        int* nidx = idxbuf[p ^ 1];

        // --- argmin over logical pairs: key=(fp64 d2, flat), all-lane result ---
        const uint32_t M = 0xFFFFFFFFu / (uint32_t)n + 1u;   // exact for flat < 2^27
        double bk = 1e300; int bp = 0x7fffffff;
        for (int flat = lane; flat < n * n; flat += 64) {
            int i = (int)__umulhi((uint32_t)flat, M);
            int j = flat - i * n;
            if (j > i) {
                double d2 = D[idx[i]][idx[j]];
                if (d2 < bk || (d2 == bk && flat < bp)) { bk = d2; bp = flat; }
            }
        }
        #pragma unroll
        for (int off = 1; off < 64; off <<= 1) {
            double ov = __shfl_xor(bk, off); int op = __shfl_xor(bp, off);
            if (ov < bk || (ov == bk && op < bp)) { bk = ov; bp = op; }
        }
        const int a   = (int)__umulhi((uint32_t)bp, M);
        const int bbj = bp - a * n;
        const int sa  = idx[a], sb = idx[bbj];

        // --- load the two rows (16-element contiguous chunk per lane) ---
        const int ra = rowaddr[sa], rb = rowaddr[sb];
        const float4* pa = (const float4*)((ra < NROWS) ? (xb + ra * CDIM)
                                                        : (rg + (ra - NROWS) * CDIM));
        const float4* pb = (const float4*)((rb < NROWS) ? (xb + rb * CDIM)
                                                        : (rg + (rb - NROWS) * CDIM));
        float xa[16], xv[16];
        #pragma unroll
        for (int q = 0; q < 4; q++) {
            float4 t = pa[lane * 4 + q];
            xa[4*q] = t.x; xa[4*q+1] = t.y; xa[4*q+2] = t.z; xa[4*q+3] = t.w;
            float4 u = pb[lane * 4 + q];
            xv[4*q] = u.x; xv[4*q+1] = u.y; xv[4*q+2] = u.z; xv[4*q+3] = u.w;
        }
        // halos across lanes (SAME padding -> zero at row ends)
        float aL = __shfl_up(xa[15], 1);   if (lane == 0)  aL = 0.0f;
        float bL = __shfl_up(xv[15], 1);   if (lane == 0)  bL = 0.0f;
        float aR = __shfl_down(xa[0], 1);  if (lane == 63) aR = 0.0f;
        float bR = __shfl_down(xv[0], 1);  if (lane == 63) bR = 0.0f;

        // --- conv + relu (fp32; matches reference fp32 conv to ~1e-7) ---
        #pragma unroll
        for (int e = 0; e < 16; e++) {
            float xm1 = (e == 0)  ? aL : xa[e - 1];
            float ym1 = (e == 0)  ? bL : xv[e - 1];
            float xp1 = (e == 15) ? aR : xa[e + 1];
            float yp1 = (e == 15) ? bR : xv[e + 1];
            float acc = cb + w00 * xm1 + w01 * xa[e] + w02 * xp1
                           + w10 * ym1 + w11 * xv[e] + w12 * yp1;
            m[e] = acc > 0.0f ? acc : 0.0f;
        }

        // --- store merged row to workspace (read back in later steps) ---
        {
            float* mdst = rg + step * CDIM;
            #pragma unroll
            for (int q = 0; q < 4; q++)
                ((float4*)mdst)[lane * 4 + q] =
                    make_float4(m[4*q], m[4*q+1], m[4*q+2], m[4*q+3]);
        }

        // --- bookkeeping: new logical order + row address of merged slot ---
        if (lane == 0) { rowaddr[sp] = NROWS + step; nidx[0] = sp; }
        if (lane >= 1 && lane < n - 1) {
            int k = lane + 1;
            int src = (k == bbj) ? 1 : ((k == a) ? 0 : k);
            nidx[lane] = idx[src];
        }

        // drain the m-store before any later global read can alias it
        __builtin_amdgcn_s_waitcnt(0);

        // --- distances merged vs survivors (fp32 diff, fp64 square-acc) ---
        #pragma unroll 2
        for (int l = 1; l < n - 1; l++) {
            const int sl = nidx[l];
            const int rr = rowaddr[sl];
            const float4* pr = (const float4*)((rr < NROWS) ? (xb + rr * CDIM)
                                                            : (rg + (rr - NROWS) * CDIM));
            double acc = 0.0;
            #pragma unroll
            for (int q = 0; q < 4; q++) {
                float4 t = pr[lane * 4 + q];
                float d0 = m[4*q]   - t.x, d1 = m[4*q+1] - t.y;
                float d2 = m[4*q+2] - t.z, d3 = m[4*q+3] - t.w;
                acc += (double)d0 * d0 + (double)d1 * d1
                     + (double)d2 * d2 + (double)d3 * d3;
            }
            #pragma unroll
            for (int off = 32; off > 0; off >>= 1) acc += __shfl_down(acc, off, 64);
            if (lane == 0) { D[sp][sl] = acc; D[sl][sp] = acc; }
        }

        sp = sb;        // slot(bb) provably dead -> next spare
        p ^= 1;
    }

    // m holds the final merged row
    float4* od = (float4*)(out + (size_t)b * CDIM);
    #pragma unroll
    for (int q = 0; q < 4; q++)
        od[lane * 4 + q] = make_float4(m[4*q], m[4*q+1], m[4*q+2], m[4*q+3]);
}

extern "C" void kernel_launch(void* const* d_in, const int* in_sizes, int n_in,
                              void* d_out, int out_size, void* d_ws, size_t ws_size,
                              hipStream_t stream) {
    const float* x  = (const float*)d_in[0]; // fp32 (512,32,1024)
    const float* w  = (const float*)d_in[1]; // fp32 (1,2,3)
    const float* cb = (const float*)d_in[2]; // fp32 (1,)
    float* out = (float*)d_out;              // fp32 (512,1024)
    char* ws   = (char*)d_ws;                // D area (4.7MB) + merged rows (65MB)
    (void)in_sizes; (void)n_in; (void)out_size; (void)ws_size;

    (void)hipFuncSetAttribute((const void*)init_d2_kernel,
                              hipFuncAttributeMaxDynamicSharedMemorySize,
                              (int)K1_LDS);

    hipLaunchKernelGGL(init_d2_kernel, dim3(BATCH), dim3(1024), K1_LDS, stream,
                       x, ws);
    hipLaunchKernelGGL(merge_kernel, dim3(BATCH), dim3(64), 0, stream,
                       x, w, cb, out, ws);
}

// Round 7
// 357.706 us; speedup vs baseline: 2.1271x; 1.4830x over previous
//
#include <hip/hip_runtime.h>
#include <stdint.h>

#define BDIM    512                   // 8 waves per batch
#define NROWS   32
#define CDIM    1024
#define NSTEPS  31
#define BATCH   512

// One 512-thread block (8 waves) per batch. Fused: init pairwise D + the
// whole 31-step merge chain. D (slot-indexed fp64, 33 slots w/ rotating
// spare) lives in LDS; alive rows live in global (originals in d_in, merged
// rows appended to d_ws) and are re-read each step (L2/L3-resident).
// Merged row of the current step is kept in LDS mrow for the distance pass.
// Argmin: wave 0, key = (fp64 d2, flat) — reference order (sqrt monotone,
// flat-index tie-break). Merged row takes the spare D-slot; next spare =
// slot(bb), provably dead every step (incl. the a==1 reference quirk where
// old row 0 is dropped). 3 barriers per step.
__global__ __launch_bounds__(BDIM)
void merge_tree_kernel(const float* __restrict__ xin,  // B*32*1024 fp32
                       const float* __restrict__ wz,   // 6 fp32 (1,2,3)
                       const float* __restrict__ bz,   // 1 fp32
                       float* __restrict__ out,        // B*1024 fp32
                       float* __restrict__ ws)         // B*31*1024 fp32 merged rows
{
    const int b    = blockIdx.x;
    const int tid  = threadIdx.x;
    const int lane = tid & 63;
    const int wid  = tid >> 6;        // 0..7

    const float* xb = xin + (size_t)b * NROWS * CDIM;
    float*       rg = ws  + (size_t)b * NSTEPS * CDIM;   // merged-row storage

    __shared__ double D[33][34];      // slot-indexed d2 (8976 B)
    __shared__ float  mrow[CDIM];     // merged row of current step
    __shared__ int    idxbuf[2][NROWS];
    __shared__ int    rowaddr[33];    // slot -> row (<32: input row, >=32: ws row-32)
    __shared__ int    sAB[2];

    const float w00 = wz[0], w01 = wz[1], w02 = wz[2];
    const float w10 = wz[3], w11 = wz[4], w12 = wz[5];
    const float cb  = bz[0];

    if (tid < NROWS) { idxbuf[0][tid] = tid; rowaddr[tid] = tid; }

    // ---------- init pairwise D: wave w takes (i, j=i+1+w+8t) ----------
    // row i cached in regs across the inner j loop; fp32 diff, fp64 sq-acc
    for (int i = 0; i < NROWS - 1; i++) {
        const float4* Ai = (const float4*)(xb + i * CDIM);
        float xa[16];
        #pragma unroll
        for (int q = 0; q < 4; q++) {
            float4 t = Ai[lane * 4 + q];
            xa[4*q] = t.x; xa[4*q+1] = t.y; xa[4*q+2] = t.z; xa[4*q+3] = t.w;
        }
        for (int j = i + 1 + wid; j < NROWS; j += 8) {
            const float4* Bj = (const float4*)(xb + j * CDIM);
            double acc = 0.0;
            #pragma unroll
            for (int q = 0; q < 4; q++) {
                float4 t = Bj[lane * 4 + q];
                float d0 = xa[4*q]   - t.x, d1 = xa[4*q+1] - t.y;
                float d2 = xa[4*q+2] - t.z, d3 = xa[4*q+3] - t.w;
                acc += (double)d0 * d0 + (double)d1 * d1
                     + (double)d2 * d2 + (double)d3 * d3;
            }
            #pragma unroll
            for (int off = 32; off > 0; off >>= 1) acc += __shfl_down(acc, off, 64);
            if (lane == 0) { D[i][j] = acc; D[j][i] = acc; }
        }
    }
    __syncthreads();

    // ---------- main merge loop: 3 barriers/step ----------
    int p = 0, sp = 32;
    for (int step = 0; step < NSTEPS; step++) {
        const int n = NROWS - step;
        int* idx  = idxbuf[p];
        int* nidx = idxbuf[p ^ 1];

        // --- argmin on wave 0: key = (fp64 d2, flat) ---
        if (wid == 0) {
            const uint32_t M = 0xFFFFFFFFu / (uint32_t)n + 1u;  // exact for flat<2^27
            double bk = 1e300; int bp = 0x7fffffff;
            for (int flat = lane; flat < n * n; flat += 64) {
                int i = (int)__umulhi((uint32_t)flat, M);
                int j = flat - i * n;
                if (j > i) {
                    double d2 = D[idx[i]][idx[j]];
                    if (d2 < bk || (d2 == bk && flat < bp)) { bk = d2; bp = flat; }
                }
            }
            #pragma unroll
            for (int off = 1; off < 64; off <<= 1) {
                double ov = __shfl_xor(bk, off); int op = __shfl_xor(bp, off);
                if (ov < bk || (ov == bk && op < bp)) { bk = ov; bp = op; }
            }
            if (lane == 0) {
                int i = (int)__umulhi((uint32_t)bp, M);
                sAB[0] = i; sAB[1] = bp - i * n;
            }
        }
        __syncthreads();                                   // B1

        const int a   = sAB[0];
        const int bbj = sAB[1];
        const int sa  = idx[a], sb = idx[bbj];
        const int ra  = rowaddr[sa], rb = rowaddr[sb];
        const float* pa = (ra < NROWS) ? (xb + ra * CDIM) : (rg + (ra - NROWS) * CDIM);
        const float* pb = (rb < NROWS) ? (xb + rb * CDIM) : (rg + (rb - NROWS) * CDIM);

        // --- conv + relu: thread -> 2 output positions (fp32 as reference) ---
        {
            const int h0 = tid * 2;
            float am1 = (h0 > 0) ? pa[h0 - 1] : 0.0f;
            float bm1 = (h0 > 0) ? pb[h0 - 1] : 0.0f;
            float a0 = pa[h0],     b0 = pb[h0];
            float a1 = pa[h0 + 1], b1 = pb[h0 + 1];
            float a2 = (h0 + 2 < CDIM) ? pa[h0 + 2] : 0.0f;
            float b2 = (h0 + 2 < CDIM) ? pb[h0 + 2] : 0.0f;
            float m0 = cb + w00 * am1 + w01 * a0 + w02 * a1
                          + w10 * bm1 + w11 * b0 + w12 * b1;
            float m1 = cb + w00 * a0 + w01 * a1 + w02 * a2
                          + w10 * b0 + w11 * b1 + w12 * b2;
            m0 = m0 > 0.0f ? m0 : 0.0f;
            m1 = m1 > 0.0f ? m1 : 0.0f;
            mrow[h0] = m0; mrow[h0 + 1] = m1;
            ((float2*)(rg + step * CDIM))[tid] = make_float2(m0, m1);
        }
        // bookkeeping: new logical order (reads old idx, writes new buffer)
        if (tid == 0) { rowaddr[sp] = NROWS + step; nidx[0] = sp; }
        if (tid >= 1 && tid < n - 1) {
            int k = tid + 1;
            int src = (k == bbj) ? 1 : ((k == a) ? 0 : k);
            nidx[tid] = idx[src];
        }
        __syncthreads();                                   // B2

        // --- distances merged(LDS) vs survivors(global): wave-striped ---
        for (int l = 1 + wid; l < n - 1; l += 8) {
            const int sl = nidx[l];
            const int rr = rowaddr[sl];
            const float* pr = (rr < NROWS) ? (xb + rr * CDIM) : (rg + (rr - NROWS) * CDIM);
            const float4* P = (const float4*)pr;
            const float4* Mv = (const float4*)mrow;
            double acc = 0.0;
            #pragma unroll
            for (int q = 0; q < 4; q++) {
                float4 t = P[lane * 4 + q];
                float4 u = Mv[lane * 4 + q];
                float d0 = u.x - t.x, d1 = u.y - t.y;
                float d2 = u.z - t.z, d3 = u.w - t.w;
                acc += (double)d0 * d0 + (double)d1 * d1
                     + (double)d2 * d2 + (double)d3 * d3;
            }
            #pragma unroll
            for (int off = 32; off > 0; off >>= 1) acc += __shfl_down(acc, off, 64);
            if (lane == 0) { D[sp][sl] = acc; D[sl][sp] = acc; }
        }
        __syncthreads();                                   // B3

        sp = sb;        // slot(bb) provably dead -> next spare
        p ^= 1;
    }

    // final merged row is in mrow
    {
        float2 v = ((const float2*)mrow)[tid];
        ((float2*)(out + (size_t)b * CDIM))[tid] = v;
    }
}

extern "C" void kernel_launch(void* const* d_in, const int* in_sizes, int n_in,
                              void* d_out, int out_size, void* d_ws, size_t ws_size,
                              hipStream_t stream) {
    const float* x  = (const float*)d_in[0]; // fp32 (512,32,1024)
    const float* w  = (const float*)d_in[1]; // fp32 (1,2,3)
    const float* cb = (const float*)d_in[2]; // fp32 (1,)
    float* out = (float*)d_out;              // fp32 (512,1024)
    float* ws  = (float*)d_ws;               // 512*31*1024 fp32 merged rows (65 MB)
    (void)in_sizes; (void)n_in; (void)out_size; (void)ws_size;

    hipLaunchKernelGGL(merge_tree_kernel, dim3(BATCH), dim3(BDIM), 0, stream,
                       x, w, cb, out, ws);
}

// Round 9
// 318.815 us; speedup vs baseline: 2.3866x; 1.1220x over previous
//
#include <hip/hip_runtime.h>
#include <stdint.h>

#define BDIM    512                   // 8 waves per batch
#define NROWS   32
#define CDIM    1024
#define NSTEPS  31
#define BATCH   512

// One 512-thread block (8 waves) per batch. ALL alive rows live in REGISTERS:
// wave w owns 4 "banks" R[0..3] = rows/slots, lane holds elements
// [lane*16 .. lane*16+15]. Merged row overwrites slot sb's bank and D-row
// (slot idx[bb] provably dead after every merge). The OTHER dead slot is
// idx[a] normally but idx[0] when a==1 (reference quirk: x[1] is both merged
// and survives at position bb; x[0] is dropped) — kill THAT bank.
// Per step, only LDS traffic: conv partials mA/mB in conflict-free [e][lane]
// layout, D (fp64, slot-indexed), idx. Argmin on wave 0: key = (fp64 d2,
// flat) — reference order (sqrt monotone, flat-index tie-break).
// 3 barriers/step. No global reads after init.
__global__ __launch_bounds__(BDIM, 4)
void merge_tree_kernel(const float* __restrict__ xin,  // B*32*1024 fp32
                       const float* __restrict__ wz,   // 6 fp32 (1,2,3)
                       const float* __restrict__ bz,   // 1 fp32
                       float* __restrict__ out)        // B*1024 fp32
{
    const int b    = blockIdx.x;
    const int tid  = threadIdx.x;
    const int lane = tid & 63;
    const int wid  = tid >> 6;        // 0..7

    const float* xb = xin + (size_t)b * NROWS * CDIM;

    __shared__ double D[NROWS][NROWS + 1];   // slot-indexed d2 (8448 B)
    __shared__ float  mA[16 * 64];           // conv partial (ch0), [e][lane]
    __shared__ float  mB[16 * 64];           // conv partial (ch1), [e][lane]
    __shared__ int    idxbuf[2][NROWS];      // logical pos -> slot
    __shared__ int    bankSlot[32];          // bank (wid*4+k) -> slot, -1 dead
    __shared__ int    sAB[2];

    const float w00 = wz[0], w01 = wz[1], w02 = wz[2];
    const float w10 = wz[3], w11 = wz[4], w12 = wz[5];
    const float cb  = bz[0];

    float R[4][16];                   // 4 owned rows (64 VGPRs)
    float m[16];                      // current merged row / temp

    // ---------- load own rows (one-time) ----------
    #pragma unroll
    for (int k = 0; k < 4; k++) {
        const float4* src = (const float4*)(xb + (size_t)(4 * wid + k) * CDIM);
        #pragma unroll
        for (int q = 0; q < 4; q++) {
            float4 t = src[lane * 4 + q];
            R[k][4*q] = t.x; R[k][4*q+1] = t.y; R[k][4*q+2] = t.z; R[k][4*q+3] = t.w;
        }
    }
    if (tid < NROWS) { idxbuf[0][tid] = tid; bankSlot[tid] = tid; }

    // ---------- init pairwise D: stream row i from global, dist vs own banks ----------
    for (int i = 0; i < NROWS - 1; i++) {
        const float4* src = (const float4*)(xb + (size_t)i * CDIM);
        #pragma unroll
        for (int q = 0; q < 4; q++) {
            float4 t = src[lane * 4 + q];
            m[4*q] = t.x; m[4*q+1] = t.y; m[4*q+2] = t.z; m[4*q+3] = t.w;
        }
        double accv[4]; int sl[4];
        #pragma unroll
        for (int k = 0; k < 4; k++) {
            const int s = 4 * wid + k;
            sl[k] = (s > i) ? s : -1;
            double acc = 0.0;
            if (s > i) {              // wave-uniform
                #pragma unroll
                for (int e = 0; e < 16; e++) {
                    float d = m[e] - R[k][e];
                    acc += (double)d * (double)d;
                }
            }
            accv[k] = acc;
        }
        #pragma unroll
        for (int k = 0; k < 4; k++) {
            if (sl[k] >= 0) {         // wave-uniform
                double acc = accv[k];
                #pragma unroll
                for (int off = 32; off > 0; off >>= 1) acc += __shfl_down(acc, off, 64);
                if (lane == 0) { D[i][sl[k]] = acc; D[sl[k]][i] = acc; }
            }
        }
    }
    __syncthreads();

    // ---------- main merge loop: 3 barriers/step ----------
    int p = 0;
    for (int step = 0; step < NSTEPS; step++) {
        const int n = NROWS - step;
        int* idx  = idxbuf[p];
        int* nidx = idxbuf[p ^ 1];

        // --- argmin on wave 0: key = (fp64 d2, flat) ---
        if (wid == 0) {
            const uint32_t M = 0xFFFFFFFFu / (uint32_t)n + 1u;  // exact for flat<2^27
            double bk = 1e300; int bp = 0x7fffffff;
            for (int flat = lane; flat < n * n; flat += 64) {
                int i = (int)__umulhi((uint32_t)flat, M);
                int j = flat - i * n;
                if (j > i) {
                    double d2 = D[idx[i]][idx[j]];
                    if (d2 < bk || (d2 == bk && flat < bp)) { bk = d2; bp = flat; }
                }
            }
            #pragma unroll
            for (int off = 1; off < 64; off <<= 1) {
                double ov = __shfl_xor(bk, off); int op = __shfl_xor(bp, off);
                if (ov < bk || (ov == bk && op < bp)) { bk = ov; bp = op; }
            }
            if (lane == 0) {
                int i = (int)__umulhi((uint32_t)bp, M);
                sAB[0] = i; sAB[1] = bp - i * n;
            }
        }
        __syncthreads();                                   // B1

        const int a   = sAB[0];
        const int bbj = sAB[1];
        const int sa  = idx[a], sb = idx[bbj];
        // dead slots this step: sb (always) and deadSlot (idx[a], or idx[0]
        // when a==1 — x[1] survives at position bb, x[0] is dropped)
        const int deadSlot = (a == 1) ? idx[0] : sa;

        // --- conv partials by owner waves, from registers, into [e][lane] LDS ---
        #pragma unroll
        for (int k = 0; k < 4; k++) {
            const int s = bankSlot[wid * 4 + k];           // own entry, wave-uniform
            if (s == sa || s == sb) {
                float hl = __shfl_up(R[k][15], 1);  if (lane == 0)  hl = 0.0f;
                float hr = __shfl_down(R[k][0], 1); if (lane == 63) hr = 0.0f;
                float* dst = (s == sa) ? mA : mB;
                const float c0 = (s == sa) ? w00 : w10;
                const float c1 = (s == sa) ? w01 : w11;
                const float c2 = (s == sa) ? w02 : w12;
                #pragma unroll
                for (int e = 0; e < 16; e++) {
                    float xm1 = (e == 0)  ? hl : R[k][e - 1];
                    float xp1 = (e == 15) ? hr : R[k][e + 1];
                    dst[e * 64 + lane] = c0 * xm1 + c1 * R[k][e] + c2 * xp1;
                }
            }
        }
        // bookkeeping: new logical order (merged keeps slot id sb)
        if (tid == 0) nidx[0] = sb;
        if (tid >= 1 && tid < n - 1) {
            int kk = tid + 1;
            int src = (kk == bbj) ? 1 : ((kk == a) ? 0 : kk);
            nidx[tid] = idx[src];
        }
        __syncthreads();                                   // B2

        // --- finalize m (all waves need it); conflict-free strided reads ---
        #pragma unroll
        for (int e = 0; e < 16; e++) {
            float v = cb + mA[e * 64 + lane] + mB[e * 64 + lane];
            m[e] = v > 0.0f ? v : 0.0f;
        }
        // owner(sb): bank <- m; owner(deadSlot): kill bank; dists vs live banks
        double accv[4]; int sl[4];
        #pragma unroll
        for (int k = 0; k < 4; k++) {
            int s = bankSlot[wid * 4 + k];
            if (s == sb) {                                 // wave-uniform
                #pragma unroll
                for (int e = 0; e < 16; e++) R[k][e] = m[e];
            }
            if (s == deadSlot) {
                if (lane == 0) bankSlot[wid * 4 + k] = -1;
                s = -1;
            }
            const int live = (s >= 0 && s != sb) ? s : -1;
            sl[k] = live;
            double acc = 0.0;
            if (live >= 0) {                               // wave-uniform
                #pragma unroll
                for (int e = 0; e < 16; e++) {
                    float d = m[e] - R[k][e];
                    acc += (double)d * (double)d;
                }
            }
            accv[k] = acc;
        }
        #pragma unroll
        for (int k = 0; k < 4; k++) {
            if (sl[k] >= 0) {                              // wave-uniform
                double acc = accv[k];
                #pragma unroll
                for (int off = 32; off > 0; off >>= 1) acc += __shfl_down(acc, off, 64);
                if (lane == 0) { D[sb][sl[k]] = acc; D[sl[k]][sb] = acc; }
            }
        }
        __syncthreads();                                   // B3
        p ^= 1;
    }

    // final merged row is in m (all waves); wave 0 writes it
    if (wid == 0) {
        float4* od = (float4*)(out + (size_t)b * CDIM);
        #pragma unroll
        for (int q = 0; q < 4; q++)
            od[lane * 4 + q] = make_float4(m[4*q], m[4*q+1], m[4*q+2], m[4*q+3]);
    }
}

extern "C" void kernel_launch(void* const* d_in, const int* in_sizes, int n_in,
                              void* d_out, int out_size, void* d_ws, size_t ws_size,
                              hipStream_t stream) {
    const float* x  = (const float*)d_in[0]; // fp32 (512,32,1024)
    const float* w  = (const float*)d_in[1]; // fp32 (1,2,3)
    const float* cb = (const float*)d_in[2]; // fp32 (1,)
    float* out = (float*)d_out;              // fp32 (512,1024)
    (void)d_ws; (void)ws_size; (void)in_sizes; (void)n_in; (void)out_size;

    hipLaunchKernelGGL(merge_tree_kernel, dim3(BATCH), dim3(BDIM), 0, stream,
                       x, w, cb, out);
}